// Round 7
// baseline (262.130 us; speedup 1.0000x reference)
//
#include <hip/hip_runtime.h>
#include <cstdint>
#include <cstddef>

// GCN on MI355X, round 7: L2-sliced agg128 + quad-wave edge parallelism.
//   out[50000,64] = log_softmax(gcn2(relu(gcn1(x))))
// agg128: 4 column-slices of 32 cols (3.2MB < 4MiB XCD L2); slice=blockIdx&3
//   so under round-robin dispatch each XCD's L2 serves one slice only.
// Both aggs: quad-split waves (4 edges in flight; lane&15 owns one uint),
//   cross-quad shfl_xor(16|32) reduction per row.

#define N_FEAT 128
#define NWAVE_A 2048   // waves per slice in agg128 (x4 slices = 8192 total)
#define NWAVE_B 8192   // waves in agg64ls

typedef short bf16x8 __attribute__((ext_vector_type(8)));
typedef float f32x4 __attribute__((ext_vector_type(4)));

__device__ __forceinline__ unsigned f2bf(float f) {
  unsigned u = __float_as_uint(f);
  return (u + 0x7FFFu + ((u >> 16) & 1u)) >> 16;   // round-to-nearest-even
}
__device__ __forceinline__ float bflo(unsigned u) { return __uint_as_float(u << 16); }
__device__ __forceinline__ float bfhi(unsigned u) { return __uint_as_float(u & 0xFFFF0000u); }

// ---------------- preprocessing ----------------

__global__ void k_hist(const int* __restrict__ dst, int* __restrict__ cnt,
                       int* __restrict__ rank, int E) {
  int e = blockIdx.x * blockDim.x + threadIdx.x;
  if (e < E) rank[e] = atomicAdd(&cnt[dst[e]], 1);
}

__global__ __launch_bounds__(256) void k_bsum(const int* __restrict__ cnt,
                                              int* __restrict__ bsum, int n) {
  int i = blockIdx.x * 256 + threadIdx.x;
  int v = (i < n) ? ((cnt[i] + 3) & ~3) : 0;
  for (int o = 32; o > 0; o >>= 1) v += __shfl_down(v, o);
  __shared__ int w[4];
  if ((threadIdx.x & 63) == 0) w[threadIdx.x >> 6] = v;
  __syncthreads();
  if (threadIdx.x == 0) bsum[blockIdx.x] = w[0] + w[1] + w[2] + w[3];
}

__global__ __launch_bounds__(256) void k_bscan(const int* __restrict__ bsum,
                                               int* __restrict__ bbase, int nb) {
  __shared__ int lds[256];
  int t = threadIdx.x;
  int v = (t < nb) ? bsum[t] : 0;
  lds[t] = v;
  __syncthreads();
  for (int o = 1; o < 256; o <<= 1) {
    int u = (t >= o) ? lds[t - o] : 0;
    __syncthreads();
    lds[t] += u;
    __syncthreads();
  }
  if (t < nb) bbase[t] = lds[t] - v;   // exclusive
}

__global__ __launch_bounds__(256) void k_scan2(const int* __restrict__ cnt,
                                               const int* __restrict__ bbase,
                                               int* __restrict__ rowptr,
                                               float* __restrict__ dinv,
                                               unsigned* __restrict__ desc, int n) {
  __shared__ int lds[256];
  int t = threadIdx.x;
  int i = blockIdx.x * 256 + t;
  int c  = (i < n) ? cnt[i] : 0;
  int pc = (c + 3) & ~3;
  lds[t] = pc;
  __syncthreads();
  for (int o = 1; o < 256; o <<= 1) {
    int u = (t >= o) ? lds[t - o] : 0;
    __syncthreads();
    lds[t] += u;
    __syncthreads();
  }
  if (i < n) {
    int excl = bbase[blockIdx.x] + lds[t] - pc;
    rowptr[i] = excl;
    dinv[i] = rsqrtf((float)(c + 1));          // +1 self-loop
    for (int p = excl + c; p < excl + pc; ++p) desc[p] = 0;  // dummy edges
    if (i == n - 1) rowptr[n] = excl + pc;
  }
}

__device__ __forceinline__ int rp_lower_bound(const int* __restrict__ rowptr,
                                              int n, int target) {
  int lo = 0, hi = n;
  while (lo < hi) {
    int mid = (lo + hi) >> 1;
    if (rowptr[mid] < target) lo = mid + 1; else hi = mid;
  }
  return lo;
}

__global__ void k_wstart(const int* __restrict__ rowptr,
                         int* __restrict__ wsA, int* __restrict__ wsB, int n) {
  int w = blockIdx.x * blockDim.x + threadIdx.x;
  int Ep = rowptr[n];
  if (w <= NWAVE_B)
    wsB[w] = (w == NWAVE_B) ? n
           : rp_lower_bound(rowptr, n, (int)((long long)Ep * w / NWAVE_B));
  if (w <= NWAVE_A)
    wsA[w] = (w == NWAVE_A) ? n
           : rp_lower_bound(rowptr, n, (int)((long long)Ep * w / NWAVE_A));
}

__global__ void k_fill(const int* __restrict__ src, const int* __restrict__ dst,
                       const int* __restrict__ rank, const int* __restrict__ rowptr,
                       const float* __restrict__ dinv,
                       unsigned* __restrict__ desc, int E) {
  int e = blockIdx.x * blockDim.x + threadIdx.x;
  if (e >= E) return;
  int s = src[e], d = dst[e];
  int p = rowptr[d] + rank[e];
  desc[p] = (f2bf(dinv[s] * dinv[d]) << 16) | (unsigned)s;
}

// ---------------- MFMA GEMMs (unchanged from round 6) ----------------

template<int NCOL, bool XF32>
__global__ __launch_bounds__(256) void k_gemm_mfma(const void* __restrict__ Xv,
                                                   const float* __restrict__ W,
                                                   unsigned short* __restrict__ Yb,
                                                   int n) {
  constexpr int NT = NCOL / 16;
  __shared__ uint4 Xl[64][16];
  __shared__ uint4 Wl[NCOL][16];
  int t = threadIdx.x;
  int row0 = blockIdx.x * 64;

  for (int c = t; c < 1024; c += 256) {
    int lr = c >> 4, kc = c & 15;
    int row = row0 + lr;
    uint4 v = {0u, 0u, 0u, 0u};
    if (row < n) {
      if constexpr (XF32) {
        const float* Xf = (const float*)Xv;
        float4 f0 = *(const float4*)(Xf + (size_t)row * 128 + kc * 8);
        float4 f1 = *(const float4*)(Xf + (size_t)row * 128 + kc * 8 + 4);
        v.x = f2bf(f0.x) | (f2bf(f0.y) << 16);
        v.y = f2bf(f0.z) | (f2bf(f0.w) << 16);
        v.z = f2bf(f1.x) | (f2bf(f1.y) << 16);
        v.w = f2bf(f1.z) | (f2bf(f1.w) << 16);
      } else {
        v = ((const uint4*)Xv)[(size_t)row * 16 + kc];
      }
    }
    Xl[lr][kc ^ (lr & 7)] = v;
  }
  {
    int j = t % NCOL, kc0 = t / NCOL;
    for (int kc = kc0; kc < 16; kc += 256 / NCOL) {
      const float* wp = W + (size_t)(kc * 8) * NCOL + j;
      float f[8];
#pragma unroll
      for (int e = 0; e < 8; ++e) f[e] = wp[e * NCOL];
      uint4 v;
      v.x = f2bf(f[0]) | (f2bf(f[1]) << 16);
      v.y = f2bf(f[2]) | (f2bf(f[3]) << 16);
      v.z = f2bf(f[4]) | (f2bf(f[5]) << 16);
      v.w = f2bf(f[6]) | (f2bf(f[7]) << 16);
      Wl[j][kc ^ (j & 7)] = v;
    }
  }
  __syncthreads();

  int w = t >> 6, lane = t & 63;
  int lr16 = lane & 15, kg = lane >> 4;
  bf16x8 a[4];
#pragma unroll
  for (int kk = 0; kk < 4; ++kk)
    a[kk] = __builtin_bit_cast(bf16x8, Xl[w * 16 + lr16][(kk * 4 + kg) ^ (lane & 7)]);
#pragma unroll
  for (int jt = 0; jt < NT; ++jt) {
    f32x4 acc = {0.0f, 0.0f, 0.0f, 0.0f};
#pragma unroll
    for (int kk = 0; kk < 4; ++kk) {
      bf16x8 b = __builtin_bit_cast(bf16x8, Wl[jt * 16 + lr16][(kk * 4 + kg) ^ (lane & 7)]);
      acc = __builtin_amdgcn_mfma_f32_16x16x32_bf16(a[kk], b, acc, 0, 0, 0);
    }
    int col = jt * 16 + lr16;
#pragma unroll
    for (int r = 0; r < 4; ++r) {
      int row = row0 + w * 16 + kg * 4 + r;
      if (row < n) Yb[(size_t)row * NCOL + col] = (unsigned short)f2bf(acc[r]);
    }
  }
}

// ---------------- aggregations ----------------

// Layer-1, sliced: slice=blockIdx&3 covers cols [32s,32s+32) (uints [16s,16s+16)).
// Quad q=lane>>4 handles edge base+q; c=lane&15 owns one uint (2 cols).
__global__ __launch_bounds__(256) void k_agg128s(const unsigned* __restrict__ desc,
                                                 const int* __restrict__ rowptr,
                                                 const int* __restrict__ wsA,
                                                 const float* __restrict__ dinv,
                                                 const float* __restrict__ bias,
                                                 const unsigned* __restrict__ xwb,
                                                 unsigned* __restrict__ hb, int n) {
  int slice = blockIdx.x & 3;
  int w     = (blockIdx.x >> 2) * 4 + (threadIdx.x >> 6);  // 0..NWAVE_A-1
  int lane  = threadIdx.x & 63;
  int q = lane >> 4, c = lane & 15;
  int r0 = wsA[w], r1 = wsA[w + 1];
  if (r0 >= r1) return;
  int co = slice * 16 + c;                 // uint index within 64-uint row
  float b0 = bias[2 * co], b1 = bias[2 * co + 1];
  int beg = rowptr[r0];
  for (int r = r0; r < r1; ++r) {
    int end = rowptr[r + 1];
    float ax = 0.0f, ay = 0.0f, bx = 0.0f, by = 0.0f;
    if (q == 0) {                          // self-loop + bias counted once
      float di = dinv[r];
      float sl = di * di;
      unsigned us = xwb[(size_t)r * 64 + co];
      ax = b0 + bflo(us) * sl;
      ay = b1 + bfhi(us) * sl;
    }
    int base = beg;
    for (; base + 8 <= end; base += 8) {   // 8 edges per iter (2 per quad)
      unsigned d0 = desc[base + q];
      unsigned d1 = desc[base + 4 + q];
      unsigned u0 = xwb[(size_t)(d0 & 0xFFFFu) * 64 + co];
      unsigned u1 = xwb[(size_t)(d1 & 0xFFFFu) * 64 + co];
      float n0 = bfhi(d0), n1 = bfhi(d1);
      ax += bflo(u0) * n0; ay += bfhi(u0) * n0;
      bx += bflo(u1) * n1; by += bfhi(u1) * n1;
    }
    if (base < end) {                      // remaining quad-group of 4
      unsigned d0 = desc[base + q];
      unsigned u0 = xwb[(size_t)(d0 & 0xFFFFu) * 64 + co];
      float n0 = bfhi(d0);
      ax += bflo(u0) * n0; ay += bfhi(u0) * n0;
    }
    ax += bx; ay += by;
    ax += __shfl_xor(ax, 16); ax += __shfl_xor(ax, 32);
    ay += __shfl_xor(ay, 16); ay += __shfl_xor(ay, 32);
    if (q == 0) {
      float ox = fmaxf(ax, 0.0f), oy = fmaxf(ay, 0.0f);
      hb[(size_t)r * 64 + co] = f2bf(ox) | (f2bf(oy) << 16);
    }
    beg = end;
  }
}

// Layer-2 + log_softmax, quad-split: quad q handles edge base+q; lane c owns
// uints {c, c+16} of the 32-uint row (cols {2c,2c+1} and {2c+32,2c+33}).
__global__ __launch_bounds__(256) void k_agg64q(const unsigned* __restrict__ desc,
                                                const int* __restrict__ rowptr,
                                                const int* __restrict__ wsB,
                                                const float* __restrict__ dinv,
                                                const float* __restrict__ bias,
                                                const unsigned* __restrict__ hwb,
                                                float* __restrict__ out, int n) {
  int w    = blockIdx.x * 4 + (threadIdx.x >> 6);          // 0..NWAVE_B-1
  int lane = threadIdx.x & 63;
  int q = lane >> 4, c = lane & 15;
  int r0 = wsB[w], r1 = wsB[w + 1];
  if (r0 >= r1) return;
  float b0 = bias[2 * c], b1 = bias[2 * c + 1];
  float b2 = bias[32 + 2 * c], b3 = bias[32 + 2 * c + 1];
  int beg = rowptr[r0];
  for (int r = r0; r < r1; ++r) {
    int end = rowptr[r + 1];
    float ax = 0.0f, ay = 0.0f, az = 0.0f, aw = 0.0f;
    if (q == 0) {                          // self-loop + bias counted once
      float di = dinv[r];
      float sl = di * di;
      unsigned us0 = hwb[(size_t)r * 32 + c];
      unsigned us1 = hwb[(size_t)r * 32 + 16 + c];
      ax = b0 + bflo(us0) * sl; ay = b1 + bfhi(us0) * sl;
      az = b2 + bflo(us1) * sl; aw = b3 + bfhi(us1) * sl;
    }
    for (int base = beg; base < end; base += 4) {
      unsigned d = desc[base + q];
      size_t sp = (size_t)(d & 0xFFFFu) * 32;
      unsigned u0 = hwb[sp + c];
      unsigned u1 = hwb[sp + 16 + c];
      float nm = bfhi(d);
      ax += bflo(u0) * nm; ay += bfhi(u0) * nm;
      az += bflo(u1) * nm; aw += bfhi(u1) * nm;
    }
    ax += __shfl_xor(ax, 16); ax += __shfl_xor(ax, 32);
    ay += __shfl_xor(ay, 16); ay += __shfl_xor(ay, 32);
    az += __shfl_xor(az, 16); az += __shfl_xor(az, 32);
    aw += __shfl_xor(aw, 16); aw += __shfl_xor(aw, 32);
    float m = fmaxf(fmaxf(ax, ay), fmaxf(az, aw));
    for (int o = 8; o > 0; o >>= 1) m = fmaxf(m, __shfl_xor(m, o));
    float s = expf(ax - m) + expf(ay - m) + expf(az - m) + expf(aw - m);
    for (int o = 8; o > 0; o >>= 1) s += __shfl_xor(s, o);
    float ls = logf(s);
    if (q == 0) {
      float2 o0 = { ax - m - ls, ay - m - ls };
      float2 o1 = { az - m - ls, aw - m - ls };
      *(float2*)(out + (size_t)r * 64 + 2 * c) = o0;
      *(float2*)(out + (size_t)r * 64 + 32 + 2 * c) = o1;
    }
    beg = end;
  }
}

extern "C" void kernel_launch(void* const* d_in, const int* in_sizes, int n_in,
                              void* d_out, int out_size, void* d_ws, size_t ws_size,
                              hipStream_t stream) {
  const float* x  = (const float*)d_in[0];
  const int*   ei = (const int*)d_in[1];
  const float* W1 = (const float*)d_in[2];
  const float* b1 = (const float*)d_in[3];
  const float* W2 = (const float*)d_in[4];
  const float* b2 = (const float*)d_in[5];
  float* out = (float*)d_out;

  const int n = in_sizes[0] / N_FEAT;   // 50000
  const int E = in_sizes[1] / 2;        // 800000
  const int* src = ei;
  const int* dst = ei + E;
  const int nb = (n + 255) / 256;       // 196

  auto align = [](size_t v) { return (v + 255) & ~(size_t)255; };
  char* ws = (char*)d_ws;
  size_t off = 0;
  int*      cnt    = (int*)     (ws + off); off += align((size_t)n * 4);
  int*      rowptr = (int*)     (ws + off); off += align((size_t)(n + 1) * 4);
  float*    dinv   = (float*)   (ws + off); off += align((size_t)n * 4);
  int*      rank   = (int*)     (ws + off); off += align((size_t)E * 4);
  int*      bsum   = (int*)     (ws + off); off += align(256 * 4);
  int*      bbase  = (int*)     (ws + off); off += align(256 * 4);
  int*      wsA    = (int*)     (ws + off); off += align((size_t)(NWAVE_A + 1) * 4);
  int*      wsB    = (int*)     (ws + off); off += align((size_t)(NWAVE_B + 1) * 4);
  unsigned* desc   = (unsigned*)(ws + off); off += align((size_t)(E + 4 * n) * 4);
  unsigned* xwb    = (unsigned*)(ws + off); off += align((size_t)n * 64 * 4);  // bf16[n,128]
  unsigned* hb     = (unsigned*)(ws + off); off += align((size_t)n * 64 * 4);  // bf16[n,128]
  unsigned* hwb    = xwb;  // bf16[n,64] overlays xwb (dead after agg128)

  hipMemsetAsync(cnt, 0, (size_t)n * 4, stream);
  k_hist<<<(E + 255) / 256, 256, 0, stream>>>(dst, cnt, rank, E);
  k_bsum<<<nb, 256, 0, stream>>>(cnt, bsum, n);
  k_bscan<<<1, 256, 0, stream>>>(bsum, bbase, nb);
  k_scan2<<<nb, 256, 0, stream>>>(cnt, bbase, rowptr, dinv, desc, n);
  k_wstart<<<(NWAVE_B + 256) / 256, 256, 0, stream>>>(rowptr, wsA, wsB, n);
  k_fill<<<(E + 255) / 256, 256, 0, stream>>>(src, dst, rank, rowptr, dinv, desc, E);

  // Layer 1
  k_gemm_mfma<128, true><<<(n + 63) / 64, 256, 0, stream>>>(
      x, W1, (unsigned short*)xwb, n);
  k_agg128s<<<NWAVE_A, 256, 0, stream>>>(desc, rowptr, wsA, dinv, b1, xwb, hb, n);

  // Layer 2
  k_gemm_mfma<64, false><<<(n + 63) / 64, 256, 0, stream>>>(
      hb, W2, (unsigned short*)hwb, n);
  k_agg64q<<<NWAVE_B / 4, 256, 0, stream>>>(desc, rowptr, wsB, dinv, b2, hwb, out, n);
}